// Round 5
// baseline (2823.957 us; speedup 1.0000x reference)
//
#include <hip/hip_runtime.h>
#include <math.h>

#define TT 160
#define EE 256
#define HH 512
#define KK 768
#define B2 512
#define BQ 256
#define N4 2048

typedef __attribute__((ext_vector_type(8)))  _Float16 half8;
typedef __attribute__((ext_vector_type(16))) float f32x16;

__device__ inline unsigned short f2h(float x){ union{_Float16 h; unsigned short u;}v; v.h=(_Float16)x; return v.u; }
__device__ inline float h2f(unsigned short u){ union{_Float16 h; unsigned short u;}v; v.u=u; return (float)v.h; }
__device__ inline unsigned int packh2(float a,float b){ union{_Float16 h[2]; unsigned int u;}v; v.h[0]=(_Float16)a; v.h[1]=(_Float16)b; return v.u; }
__device__ inline float sigmf(float x){ return 1.0f/(1.0f+expf(-x)); }

__device__ inline void gload_lds16(const void* g, void* l){
    __builtin_amdgcn_global_load_lds(
        (const __attribute__((address_space(1))) void*)g,
        (__attribute__((address_space(3))) void*)l, 16, 0, 0);
}

// ---------------------------------------------------------------------------
// Wt[unit*4+gate][k] = fp16(W[k][gate*512+unit])   (gates interleaved per unit)
__global__ __launch_bounds__(256) void transposeW(const float* __restrict__ W,
                                                  unsigned short* __restrict__ Wt) {
    __shared__ float tile[32][33];
    const int tx = threadIdx.x & 31, ty = threadIdx.x >> 5;
    const int cb = blockIdx.x * 32;
    const int kb = blockIdx.y * 32;
    #pragma unroll
    for (int j = 0; j < 4; j++)
        tile[ty + j * 8][tx] = W[(size_t)(kb + ty + j * 8) * N4 + cb + tx];
    __syncthreads();
    #pragma unroll
    for (int j = 0; j < 4; j++) {
        int cl = ty + j * 8;
        int col = cb + cl;
        int gate = col >> 9, unit = col & 511;
        Wt[(size_t)(unit * 4 + gate) * KK + kb + tx] = f2h(tile[tx][cl]);
    }
}

// ---------------------------------------------------------------------------
// xseq[t*512+row][k] = fp16(emb[ids[row][t]][k])  — one wave per (t,row)
__global__ __launch_bounds__(256) void xprep(const float* __restrict__ emb,
                                             const int* __restrict__ qids,
                                             const int* __restrict__ rids,
                                             unsigned short* __restrict__ xseq) {
    const int widx = blockIdx.x * 4 + (threadIdx.x >> 6);
    const int lane = threadIdx.x & 63;
    const int row  = widx & 511;
    const int t    = widx >> 9;
    const int id   = (row < BQ) ? qids[row * TT + t] : rids[(row - BQ) * TT + t];
    const float4 f = *(const float4*)&emb[(size_t)id * EE + lane * 4];
    *(uint2*)&xseq[(size_t)widx * EE + lane * 4] =
        make_uint2(packh2(f.x, f.y), packh2(f.z, f.w));
}

// ---------------------------------------------------------------------------
// Persistent LSTM: all 160 steps. Grid 256 blocks (1/CU), 4 waves each.
// Block (g=bid&7, bc=bid>>3): rows [g*64,+64), units [bc*16,+16) (=64 cols').
// W panel resident in registers (48 half8/lane). A triple-buffered in LDS.
// Per-step cross-block exchange: fp16 h, guarded by per-group spin barrier.
// bid&7 == g keeps a group's 32 blocks on one XCD under round-robin dispatch
// (locality heuristic only; correctness is from agent-scope fences).
__global__ __launch_bounds__(256, 1) void lstm_persist(
    const unsigned short* __restrict__ Wt,
    const unsigned short* __restrict__ xseq,
    const float* __restrict__ bias,
    const float* __restrict__ wi_, const float* __restrict__ wf_,
    const float* __restrict__ wo_,
    const int* __restrict__ qlen, const int* __restrict__ rlen,
    unsigned short* __restrict__ hbA, unsigned short* __restrict__ hbB,
    unsigned int* __restrict__ bar)
{
    __shared__ unsigned short Abuf[3][64][128];     // 48 KB; zb overlays Abuf[2]
    float* zb = (float*)&Abuf[2][0][0];             // [64][64] f32

    const int tid = threadIdx.x;
    const int bid = blockIdx.x;
    const int g   = bid & 7;
    const int bc  = bid >> 3;
    const int rb  = g * 64;
    const int l = tid & 63, w = tid >> 6;
    const int wr = w >> 1, wc = w & 1;

    // ---- resident W fragments: wave covers cols' bc*64 + wc*32 + (l&31)
    half8 wfrag[48];
    {
        const int colp = bc * 64 + wc * 32 + (l & 31);
        const unsigned short* wrow = Wt + (size_t)colp * KK + (l >> 5) * 8;
        #pragma unroll
        for (int f = 0; f < 48; f++) wfrag[f] = *(const half8*)(wrow + 16 * f);
    }

    // ---- epilogue constants (thread owns unit u, rows rloc*4..+4)
    const int u = tid & 15;
    const int rloc = tid >> 4;
    const int Ug = bc * 16 + u;
    const float bZi = bias[Ug], bZj = bias[HH + Ug];
    const float bZf = bias[2 * HH + Ug], bZo = bias[3 * HH + Ug];
    const float wih = wi_[Ug], wfh = wf_[Ug], woh = wo_[Ug];
    int len4[4]; float c4[4], h4[4];
    #pragma unroll
    for (int i = 0; i < 4; i++) {
        int R = rb + rloc * 4 + i;
        len4[i] = (R < BQ) ? qlen[R] : rlen[R - BQ];
        c4[i] = 0.f; h4[i] = 0.f;
    }

    // stage chunk tk (128 k) of step t into buf. Wave w stages rows [w*16,+16).
    // LDS dest linear (wave-uniform base + lane*16); XOR-swizzle folded into
    // per-lane SOURCE address (rule #21: same involution as the read).
    auto stage = [&](int tk, int buf, int t, const unsigned short* hsrc) {
        #pragma unroll
        for (int i2 = 0; i2 < 4; i2++) {
            const int rowbase = w * 16 + i2 * 4;
            const int row = rowbase + (l >> 4);
            const int cch = l & 15;
            const int srcElem = (cch ^ (row & 15)) << 3;
            const unsigned short* src;
            if (tk < 2) src = xseq + ((size_t)(t * B2 + rb + row) * EE + tk * 128 + srcElem);
            else        src = hsrc + ((size_t)(rb + row) * HH + (tk - 2) * 128 + srcElem);
            gload_lds16(src, &Abuf[buf][rowbase][0]);
        }
    };

    auto compute = [&](int tk, int buf, f32x16* a0, f32x16* a1) {
        const int ra = wr * 32 + (l & 31);
        const int kg = l >> 5;
        #pragma unroll
        for (int f8 = 0; f8 < 8; f8++) {
            const int kc = f8 * 2 + kg;
            half8 av = *(const half8*)&Abuf[buf][ra][(kc ^ (ra & 15)) << 3];
            if (f8 & 1) *a1 = __builtin_amdgcn_mfma_f32_32x32x16_f16(av, wfrag[tk * 8 + f8], *a1, 0, 0, 0);
            else        *a0 = __builtin_amdgcn_mfma_f32_32x32x16_f16(av, wfrag[tk * 8 + f8], *a0, 0, 0, 0);
        }
    };

    // prologue: stage step-0 chunks 0,1 (x part; h0 = zeros staged in-loop)
    stage(0, 0, 0, hbA);
    stage(1, 1, 0, hbA);

    #pragma unroll 1
    for (int t = 0; t < TT; t++) {
        const unsigned short* hbp = (t & 1) ? hbB : hbA;
        unsigned short* hbq       = (t & 1) ? hbA : hbB;
        f32x16 acc0 = {0,0,0,0,0,0,0,0,0,0,0,0,0,0,0,0};
        f32x16 acc1 = {0,0,0,0,0,0,0,0,0,0,0,0,0,0,0,0};

        // chunk m lives in buf m%3; stage(tk+2) targets a buf whose last read
        // was chunk tk-1 (>=1 barrier behind) -> no WAR race.
        #pragma unroll
        for (int tk = 0; tk < 6; tk++) {
            __syncthreads();                 // also drains vmcnt (gload_lds)
            compute(tk, tk % 3, &acc0, &acc1);
            if (tk < 4) stage(tk + 2, (tk + 2) % 3, t, hbp);
        }
        __syncthreads();

        // ---- z exchange (zb overlays Abuf[2]; chunk-5 reads done at sync above)
        {
            const int colb = wc * 32 + (l & 31);
            const int rowb = wr * 32 + 4 * (l >> 5);
            const f32x16 s = acc0 + acc1;
            #pragma unroll
            for (int r = 0; r < 16; r++) {
                const int row = rowb + (r & 3) + 8 * (r >> 2);
                zb[row * 64 + colb] = s[r];
            }
        }
        __syncthreads();

        // ---- fused peephole cell (gate order i, j, f, o); c,h in registers
        #pragma unroll
        for (int i = 0; i < 4; i++) {
            const int row = rloc * 4 + i;
            const float4 z4 = *(const float4*)&zb[row * 64 + u * 4];
            if (t < len4[i]) {
                const float cp = c4[i];
                const float ig = sigmf(z4.x + bZi + wih * cp);
                const float jg = tanhf(z4.y + bZj);
                const float fg = sigmf(z4.z + bZf + 2.0f + wfh * cp);
                const float cn = fg * cp + ig * jg;
                const float og = sigmf(z4.w + bZo + woh * cn);
                c4[i] = cn;
                h4[i] = og * tanhf(cn);
            }
            hbq[(size_t)(rb + row) * HH + Ug] = f2h(h4[i]);
        }

        if (t < TT - 1) {
            __syncthreads();                       // all h stores issued
            if (tid == 0) {
                __threadfence();                   // agent release
                __hip_atomic_fetch_add(&bar[g * 16], 1u, __ATOMIC_RELAXED,
                                       __HIP_MEMORY_SCOPE_AGENT);
            }
            // overlap barrier wait with next step's x staging (xseq: read-only)
            stage(0, 0, t + 1, hbq);
            stage(1, 1, t + 1, hbq);
            if (tid == 0) {
                const unsigned int target = 32u * (unsigned)(t + 1);
                while (__hip_atomic_load(&bar[g * 16], __ATOMIC_RELAXED,
                                         __HIP_MEMORY_SCOPE_AGENT) < target)
                    __builtin_amdgcn_s_sleep(2);
                __threadfence();                   // agent acquire
            }
            __syncthreads();
        }
    }
    // 160 steps: final h in hbA (q rows 0..255, r rows 256..511)
}

// ---------------------------------------------------------------------------
// q_proj[256,512] = h_q(fp16)[256,512] @ M[512,512]
__global__ __launch_bounds__(512) void proj_kernel(
    const unsigned short* __restrict__ h, const float* __restrict__ M,
    float* __restrict__ qp)
{
    const int i = blockIdx.x;
    const int j = threadIdx.x;
    float s = 0.0f;
    for (int k = 0; k < HH; k++) s += h2f(h[(size_t)i * HH + k]) * M[(size_t)k * HH + j];
    qp[(size_t)i * HH + j] = s;
}

// C[256,256] = A[256,512] @ B(fp16)[256,512]^T
__global__ __launch_bounds__(256) void nt_gemm(
    const float* __restrict__ A,
    const unsigned short* __restrict__ B0, const unsigned short* __restrict__ B1,
    float* __restrict__ C0, float* __restrict__ C1)
{
    const unsigned short* Bm = blockIdx.z ? B1 : B0;
    float* Cm                = blockIdx.z ? C1 : C0;
    __shared__ float sA[16][17];
    __shared__ float sB[16][17];
    const int ti = threadIdx.x >> 4;
    const int tj = threadIdx.x & 15;
    const int ib = blockIdx.y * 16;
    const int jb = blockIdx.x * 16;
    float acc = 0.0f;
    for (int kk = 0; kk < HH; kk += 16) {
        sA[ti][tj] = A[(size_t)(ib + ti) * HH + kk + tj];
        sB[ti][tj] = h2f(Bm[(size_t)(jb + ti) * HH + kk + tj]);
        __syncthreads();
        #pragma unroll
        for (int k = 0; k < 16; k++) acc += sA[ti][k] * sB[tj][k];
        __syncthreads();
    }
    Cm[(size_t)(ib + ti) * 256 + jb + tj] = acc;
}

__global__ void diag_kernel(const float* __restrict__ dist, float* __restrict__ pos) {
    int i = threadIdx.x;
    pos[i] = dist[(size_t)i * 256 + i];
}

// ---------------------------------------------------------------------------
extern "C" void kernel_launch(void* const* d_in, const int* in_sizes, int n_in,
                              void* d_out, int out_size, void* d_ws, size_t ws_size,
                              hipStream_t stream) {
    const int*   qids = (const int*)d_in[0];
    const int*   rids = (const int*)d_in[1];
    const int*   qlen = (const int*)d_in[2];
    const int*   rlen = (const int*)d_in[3];
    const float* emb  = (const float*)d_in[4];
    const float* W    = (const float*)d_in[5];
    const float* bias = (const float*)d_in[6];
    const float* wi   = (const float*)d_in[7];
    const float* wf   = (const float*)d_in[8];
    const float* wo   = (const float*)d_in[9];
    const float* M    = (const float*)d_in[10];

    float* out       = (float*)d_out;
    float* distances = out;
    float* echo      = out + 256 * 256;
    float* pos       = out + 2 * 256 * 256;

    char* ws = (char*)d_ws;
    unsigned short* Wt   = (unsigned short*)(ws);                 // 3,145,728 B
    unsigned short* xseq = (unsigned short*)(ws + 3145728);       // 41,943,040 B
    unsigned short* hbA  = (unsigned short*)(ws + 45088768);      // 524,288 B
    unsigned short* hbB  = (unsigned short*)(ws + 45613056);      // 524,288 B
    float*          qp   = (float*)(ws + 46137344);               // 524,288 B
    unsigned int*   bar  = (unsigned int*)(ws + 46661632);        // 4,096 B

    transposeW<<<dim3(64, 24), dim3(256), 0, stream>>>(W, Wt);
    xprep<<<dim3(TT * B2 / 4), dim3(256), 0, stream>>>(emb, qids, rids, xseq);
    hipMemsetAsync(hbA, 0, 524288, stream);
    hipMemsetAsync(bar, 0, 4096, stream);

    lstm_persist<<<dim3(256), dim3(256), 0, stream>>>(
        Wt, xseq, bias, wi, wf, wo, qlen, rlen, hbA, hbB, bar);

    proj_kernel<<<dim3(256), dim3(512), 0, stream>>>(hbA, M, qp);
    nt_gemm<<<dim3(16, 16, 2), dim3(256), 0, stream>>>(
        qp, hbA + (size_t)BQ * HH /*r_enc*/, hbA /*q_enc*/, distances, echo);
    diag_kernel<<<dim3(1), dim3(256), 0, stream>>>(distances, pos);
}

// Round 6
// 1030.091 us; speedup vs baseline: 2.7415x; 2.7415x over previous
//
#include <hip/hip_runtime.h>
#include <math.h>

#define TT 160
#define EE 256
#define HH 512
#define KK 768
#define B2 512
#define BQ 256
#define N4 2048

typedef __attribute__((ext_vector_type(8)))  _Float16 half8;
typedef __attribute__((ext_vector_type(16))) float f32x16;

__device__ inline unsigned short f2h(float x){ union{_Float16 h; unsigned short u;}v; v.h=(_Float16)x; return v.u; }
__device__ inline float h2f(unsigned short u){ union{_Float16 h; unsigned short u;}v; v.u=u; return (float)v.h; }
__device__ inline unsigned int packh2(float a,float b){ union{_Float16 h[2]; unsigned int u;}v; v.h[0]=(_Float16)a; v.h[1]=(_Float16)b; return v.u; }
__device__ inline float sigmf(float x){ return 1.0f/(1.0f+expf(-x)); }

// cached (L1/L2) global->LDS, 16B/lane
__device__ inline void gload_lds16_c(const void* g, void* l){
    __builtin_amdgcn_global_load_lds(
        (const __attribute__((address_space(1))) void*)g,
        (__attribute__((address_space(3))) void*)l, 16, 0, 0);
}
// device-coherent global->LDS: SC0|SC1 (bypass L1/L2, read coherence point)
__device__ inline void gload_lds16_sc(const void* g, void* l){
    __builtin_amdgcn_global_load_lds(
        (const __attribute__((address_space(1))) void*)g,
        (__attribute__((address_space(3))) void*)l, 16, 0, 0x11);
}

// ---------------------------------------------------------------------------
// Wt[unit*4+gate][k] = fp16(W[k][gate*512+unit])   (gates interleaved per unit)
__global__ __launch_bounds__(256) void transposeW(const float* __restrict__ W,
                                                  unsigned short* __restrict__ Wt) {
    __shared__ float tile[32][33];
    const int tx = threadIdx.x & 31, ty = threadIdx.x >> 5;
    const int cb = blockIdx.x * 32;
    const int kb = blockIdx.y * 32;
    #pragma unroll
    for (int j = 0; j < 4; j++)
        tile[ty + j * 8][tx] = W[(size_t)(kb + ty + j * 8) * N4 + cb + tx];
    __syncthreads();
    #pragma unroll
    for (int j = 0; j < 4; j++) {
        int cl = ty + j * 8;
        int col = cb + cl;
        int gate = col >> 9, unit = col & 511;
        Wt[(size_t)(unit * 4 + gate) * KK + kb + tx] = f2h(tile[tx][cl]);
    }
}

// ---------------------------------------------------------------------------
// xseq[t*512+row][k] = fp16(emb[ids[row][t]][k])  — one wave per (t,row)
__global__ __launch_bounds__(256) void xprep(const float* __restrict__ emb,
                                             const int* __restrict__ qids,
                                             const int* __restrict__ rids,
                                             unsigned short* __restrict__ xseq) {
    const int widx = blockIdx.x * 4 + (threadIdx.x >> 6);
    const int lane = threadIdx.x & 63;
    const int row  = widx & 511;
    const int t    = widx >> 9;
    const int id   = (row < BQ) ? qids[row * TT + t] : rids[(row - BQ) * TT + t];
    const float4 f = *(const float4*)&emb[(size_t)id * EE + lane * 4];
    *(uint2*)&xseq[(size_t)widx * EE + lane * 4] =
        make_uint2(packh2(f.x, f.y), packh2(f.z, f.w));
}

// ---------------------------------------------------------------------------
// Persistent LSTM: all 160 steps. Grid 256 blocks (1/CU), 4 waves each.
// Block (g=bid&7, bc=bid>>3): rows [g*64,+64), units [bc*16,+16) (=64 cols').
// W panel resident in registers (48 half8/lane). A triple-buffered in LDS.
// Cross-block h exchange: device-coherent accesses (sc0|sc1), NO cache-wide
// fences. Per-group relaxed-atomic spin barrier; release ordering from the
// vmcnt(0) drain at __syncthreads before the post.
__global__ __launch_bounds__(256, 1) void lstm_persist(
    const unsigned short* __restrict__ Wt,
    const unsigned short* __restrict__ xseq,
    const float* __restrict__ bias,
    const float* __restrict__ wi_, const float* __restrict__ wf_,
    const float* __restrict__ wo_,
    const int* __restrict__ qlen, const int* __restrict__ rlen,
    unsigned short* __restrict__ hbA, unsigned short* __restrict__ hbB,
    unsigned int* __restrict__ bar)
{
    __shared__ unsigned short Abuf[3][64][128];     // 48 KB; zb overlays Abuf[2]
    float* zb = (float*)&Abuf[2][0][0];             // [64][64] f32, f4-col swizzled

    const int tid = threadIdx.x;
    const int bid = blockIdx.x;
    const int g   = bid & 7;
    const int bc  = bid >> 3;
    const int rb  = g * 64;
    const int l = tid & 63, w = tid >> 6;
    const int wr = w >> 1, wc = w & 1;

    // ---- resident W fragments: wave covers cols' bc*64 + wc*32 + (l&31)
    half8 wfrag[48];
    {
        const int colp = bc * 64 + wc * 32 + (l & 31);
        const unsigned short* wrow = Wt + (size_t)colp * KK + (l >> 5) * 8;
        #pragma unroll
        for (int f = 0; f < 48; f++) wfrag[f] = *(const half8*)(wrow + 16 * f);
    }

    // ---- epilogue: thread owns 1 row (erow) x 4 contiguous units (eu..eu+3)
    const int erow = tid >> 2;
    const int eu   = (tid & 3) << 2;
    const int Ug0  = bc * 16 + eu;
    const float4 b_i = *(const float4*)&bias[Ug0];
    const float4 b_j = *(const float4*)&bias[HH + Ug0];
    const float4 b_f = *(const float4*)&bias[2 * HH + Ug0];
    const float4 b_o = *(const float4*)&bias[3 * HH + Ug0];
    const float4 wiv = *(const float4*)&wi_[Ug0];
    const float4 wfv = *(const float4*)&wf_[Ug0];
    const float4 wov = *(const float4*)&wo_[Ug0];
    const int len = (rb + erow < BQ) ? qlen[rb + erow] : rlen[rb + erow - BQ];
    float cc[4] = {0.f,0.f,0.f,0.f}, hh[4] = {0.f,0.f,0.f,0.f};

    // stage chunk tk (128 k) of step t into buf. Wave w stages rows [w*16,+16).
    // LDS dest linear; XOR-swizzle folded into per-lane SOURCE address.
    // h chunks (tk>=2) use device-coherent loads.
    auto stage = [&](int tk, int buf, int t, const unsigned short* hsrc) {
        #pragma unroll
        for (int i2 = 0; i2 < 4; i2++) {
            const int rowbase = w * 16 + i2 * 4;
            const int row = rowbase + (l >> 4);
            const int cch = l & 15;
            const int srcElem = (cch ^ (row & 15)) << 3;
            if (tk < 2) {
                const unsigned short* src =
                    xseq + ((size_t)(t * B2 + rb + row) * EE + tk * 128 + srcElem);
                gload_lds16_c(src, &Abuf[buf][rowbase][0]);
            } else {
                const unsigned short* src =
                    hsrc + ((size_t)(rb + row) * HH + (tk - 2) * 128 + srcElem);
                gload_lds16_sc(src, &Abuf[buf][rowbase][0]);
            }
        }
    };

    auto compute = [&](int tk, int buf, f32x16* a0, f32x16* a1) {
        const int ra = wr * 32 + (l & 31);
        const int kg = l >> 5;
        #pragma unroll
        for (int f8 = 0; f8 < 8; f8++) {
            const int kc = f8 * 2 + kg;
            half8 av = *(const half8*)&Abuf[buf][ra][(kc ^ (ra & 15)) << 3];
            if (f8 & 1) *a1 = __builtin_amdgcn_mfma_f32_32x32x16_f16(av, wfrag[tk * 8 + f8], *a1, 0, 0, 0);
            else        *a0 = __builtin_amdgcn_mfma_f32_32x32x16_f16(av, wfrag[tk * 8 + f8], *a0, 0, 0, 0);
        }
    };

    // prologue: stage step-0 x chunks
    stage(0, 0, 0, hbA);
    stage(1, 1, 0, hbA);
    __syncthreads();

    #pragma unroll 1
    for (int t = 0; t < TT; t++) {
        const unsigned short* hbp = (t & 1) ? hbB : hbA;
        unsigned short* hbq       = (t & 1) ? hbA : hbB;
        f32x16 acc0 = {0,0,0,0,0,0,0,0,0,0,0,0,0,0,0,0};
        f32x16 acc1 = {0,0,0,0,0,0,0,0,0,0,0,0,0,0,0,0};

        // A: x-compute chunk0; overlap the group-barrier wait
        compute(0, 0, &acc0, &acc1);
        if (t > 0 && tid == 0) {
            const unsigned int target = 32u * (unsigned)t;
            while (__hip_atomic_load(&bar[g * 16], __ATOMIC_RELAXED,
                                     __HIP_MEMORY_SCOPE_AGENT) < target)
                __builtin_amdgcn_s_sleep(1);
        }
        __syncthreads();                       // h of step t now readable

        // B: stage first h chunks; compute chunk1
        stage(2, 2, t, hbp);
        stage(3, 0, t, hbp);                   // b0: c0 reads done pre-sync
        compute(1, 1, &acc0, &acc1);
        __syncthreads();

        // C
        compute(2, 2, &acc0, &acc1);
        stage(4, 1, t, hbp);                   // b1: c1 reads done pre-sync
        __syncthreads();

        // D
        compute(3, 0, &acc0, &acc1);
        stage(5, 2, t, hbp);                   // b2: c2 reads done pre-sync
        __syncthreads();

        // E
        compute(4, 1, &acc0, &acc1);
        if (t < TT - 1) stage(0, 0, t + 1, hbp);  // x of t+1 (no barrier dep)
        __syncthreads();

        // F
        compute(5, 2, &acc0, &acc1);
        if (t < TT - 1) stage(1, 1, t + 1, hbp);
        __syncthreads();

        // G: z exchange into zb (overlays b2; c5 reads done pre-sync).
        // float4-column XOR swizzle to keep both write and read ~conflict-free.
        {
            const int colb = wc * 32 + (l & 31);
            const int c4i = colb >> 2, cr = colb & 3;
            const f32x16 s = acc0 + acc1;
            #pragma unroll
            for (int r = 0; r < 16; r++) {
                const int row = wr * 32 + 4 * (l >> 5) + (r & 3) + 8 * (r >> 2);
                zb[row * 64 + ((c4i ^ (row & 15)) << 2) + cr] = s[r];
            }
        }
        __syncthreads();

        // H: fused peephole cell (gate order i, j, f, o); 8B coherent h-store
        {
            if (t < len) {
                #pragma unroll
                for (int j = 0; j < 4; j++) {
                    const float4 z4 = *(const float4*)
                        &zb[erow * 64 + (((eu + j) ^ (erow & 15)) << 2)];
                    const float cp = cc[j];
                    const float ig = sigmf(z4.x + (&b_i.x)[j] + (&wiv.x)[j] * cp);
                    const float jg = tanhf(z4.y + (&b_j.x)[j]);
                    const float fg = sigmf(z4.z + (&b_f.x)[j] + 2.0f + (&wfv.x)[j] * cp);
                    const float cn = fg * cp + ig * jg;
                    const float og = sigmf(z4.w + (&b_o.x)[j] + (&wov.x)[j] * cn);
                    cc[j] = cn;
                    hh[j] = og * tanhf(cn);
                }
            }
            union { unsigned short s[4]; unsigned long long v; } pk;
            #pragma unroll
            for (int j = 0; j < 4; j++) pk.s[j] = f2h(hh[j]);
            __hip_atomic_store(
                (unsigned long long*)&hbq[(size_t)(rb + erow) * HH + Ug0], pk.v,
                __ATOMIC_RELAXED, __HIP_MEMORY_SCOPE_AGENT);
        }
        __syncthreads();                       // drains h stores (vmcnt 0)

        // I: post group barrier (release: stores drained at sync above)
        if (t < TT - 1 && tid == 0)
            __hip_atomic_fetch_add(&bar[g * 16], 1u, __ATOMIC_RELAXED,
                                   __HIP_MEMORY_SCOPE_AGENT);
    }
    // 160 steps (even): final h in hbA (q rows 0..255, r rows 256..511)
}

// ---------------------------------------------------------------------------
// q_proj[256,512] = h_q(fp16)[256,512] @ M[512,512]
__global__ __launch_bounds__(512) void proj_kernel(
    const unsigned short* __restrict__ h, const float* __restrict__ M,
    float* __restrict__ qp)
{
    const int i = blockIdx.x;
    const int j = threadIdx.x;
    float s = 0.0f;
    for (int k = 0; k < HH; k++) s += h2f(h[(size_t)i * HH + k]) * M[(size_t)k * HH + j];
    qp[(size_t)i * HH + j] = s;
}

// C[256,256] = A[256,512] @ B(fp16)[256,512]^T
__global__ __launch_bounds__(256) void nt_gemm(
    const float* __restrict__ A,
    const unsigned short* __restrict__ B0, const unsigned short* __restrict__ B1,
    float* __restrict__ C0, float* __restrict__ C1)
{
    const unsigned short* Bm = blockIdx.z ? B1 : B0;
    float* Cm                = blockIdx.z ? C1 : C0;
    __shared__ float sA[16][17];
    __shared__ float sB[16][17];
    const int ti = threadIdx.x >> 4;
    const int tj = threadIdx.x & 15;
    const int ib = blockIdx.y * 16;
    const int jb = blockIdx.x * 16;
    float acc = 0.0f;
    for (int kk = 0; kk < HH; kk += 16) {
        sA[ti][tj] = A[(size_t)(ib + ti) * HH + kk + tj];
        sB[ti][tj] = h2f(Bm[(size_t)(jb + ti) * HH + kk + tj]);
        __syncthreads();
        #pragma unroll
        for (int k = 0; k < 16; k++) acc += sA[ti][k] * sB[tj][k];
        __syncthreads();
    }
    Cm[(size_t)(ib + ti) * 256 + jb + tj] = acc;
}

__global__ void diag_kernel(const float* __restrict__ dist, float* __restrict__ pos) {
    int i = threadIdx.x;
    pos[i] = dist[(size_t)i * 256 + i];
}

// ---------------------------------------------------------------------------
extern "C" void kernel_launch(void* const* d_in, const int* in_sizes, int n_in,
                              void* d_out, int out_size, void* d_ws, size_t ws_size,
                              hipStream_t stream) {
    const int*   qids = (const int*)d_in[0];
    const int*   rids = (const int*)d_in[1];
    const int*   qlen = (const int*)d_in[2];
    const int*   rlen = (const int*)d_in[3];
    const float* emb  = (const float*)d_in[4];
    const float* W    = (const float*)d_in[5];
    const float* bias = (const float*)d_in[6];
    const float* wi   = (const float*)d_in[7];
    const float* wf   = (const float*)d_in[8];
    const float* wo   = (const float*)d_in[9];
    const float* M    = (const float*)d_in[10];

    float* out       = (float*)d_out;
    float* distances = out;
    float* echo      = out + 256 * 256;
    float* pos       = out + 2 * 256 * 256;

    char* ws = (char*)d_ws;
    unsigned short* Wt   = (unsigned short*)(ws);                 // 3,145,728 B
    unsigned short* xseq = (unsigned short*)(ws + 3145728);       // 41,943,040 B
    unsigned short* hbA  = (unsigned short*)(ws + 45088768);      // 524,288 B
    unsigned short* hbB  = (unsigned short*)(ws + 45613056);      // 524,288 B
    float*          qp   = (float*)(ws + 46137344);               // 524,288 B
    unsigned int*   bar  = (unsigned int*)(ws + 46661632);        // 4,096 B

    transposeW<<<dim3(64, 24), dim3(256), 0, stream>>>(W, Wt);
    xprep<<<dim3(TT * B2 / 4), dim3(256), 0, stream>>>(emb, qids, rids, xseq);
    hipMemsetAsync(hbA, 0, 524288, stream);
    hipMemsetAsync(bar, 0, 4096, stream);

    lstm_persist<<<dim3(256), dim3(256), 0, stream>>>(
        Wt, xseq, bias, wi, wf, wo, qlen, rlen, hbA, hbB, bar);

    proj_kernel<<<dim3(256), dim3(512), 0, stream>>>(hbA, M, qp);
    nt_gemm<<<dim3(16, 16, 2), dim3(256), 0, stream>>>(
        qp, hbA + (size_t)BQ * HH /*r_enc*/, hbA /*q_enc*/, distances, echo);
    diag_kernel<<<dim3(1), dim3(256), 0, stream>>>(distances, pos);
}

// Round 7
// 869.124 us; speedup vs baseline: 3.2492x; 1.1852x over previous
//
#include <hip/hip_runtime.h>
#include <math.h>

#define TT 160
#define EE 256
#define HH 512
#define KK 768
#define B2 512
#define BQ 256
#define N4 2048

typedef __attribute__((ext_vector_type(8)))  _Float16 half8;
typedef __attribute__((ext_vector_type(16))) float f32x16;

__device__ inline unsigned short f2h(float x){ union{_Float16 h; unsigned short u;}v; v.h=(_Float16)x; return v.u; }
__device__ inline float h2f(unsigned short u){ union{_Float16 h; unsigned short u;}v; v.u=u; return (float)v.h; }
__device__ inline unsigned int packh2(float a,float b){ union{_Float16 h[2]; unsigned int u;}v; v.h[0]=(_Float16)a; v.h[1]=(_Float16)b; return v.u; }
__device__ inline float sigmf(float x){ return 1.0f/(1.0f+expf(-x)); }

// cached (L1/L2) global->LDS, 16B/lane
__device__ inline void gload_lds16_c(const void* g, void* l){
    __builtin_amdgcn_global_load_lds(
        (const __attribute__((address_space(1))) void*)g,
        (__attribute__((address_space(3))) void*)l, 16, 0, 0);
}
// device-coherent global->LDS: SC0|SC1 (bypass L1/L2, read coherence point)
__device__ inline void gload_lds16_sc(const void* g, void* l){
    __builtin_amdgcn_global_load_lds(
        (const __attribute__((address_space(1))) void*)g,
        (__attribute__((address_space(3))) void*)l, 16, 0, 0x11);
}

// ---------------------------------------------------------------------------
// Wt[unit*4+gate][k] = fp16(W[k][gate*512+unit])   (gates interleaved per unit)
__global__ __launch_bounds__(256) void transposeW(const float* __restrict__ W,
                                                  unsigned short* __restrict__ Wt) {
    __shared__ float tile[32][33];
    const int tx = threadIdx.x & 31, ty = threadIdx.x >> 5;
    const int cb = blockIdx.x * 32;
    const int kb = blockIdx.y * 32;
    #pragma unroll
    for (int j = 0; j < 4; j++)
        tile[ty + j * 8][tx] = W[(size_t)(kb + ty + j * 8) * N4 + cb + tx];
    __syncthreads();
    #pragma unroll
    for (int j = 0; j < 4; j++) {
        int cl = ty + j * 8;
        int col = cb + cl;
        int gate = col >> 9, unit = col & 511;
        Wt[(size_t)(unit * 4 + gate) * KK + kb + tx] = f2h(tile[tx][cl]);
    }
}

// ---------------------------------------------------------------------------
// xseq[t*512+row][k] = fp16(emb[ids[row][t]][k])  — one wave per (t,row)
__global__ __launch_bounds__(256) void xprep(const float* __restrict__ emb,
                                             const int* __restrict__ qids,
                                             const int* __restrict__ rids,
                                             unsigned short* __restrict__ xseq) {
    const int widx = blockIdx.x * 4 + (threadIdx.x >> 6);
    const int lane = threadIdx.x & 63;
    const int row  = widx & 511;
    const int t    = widx >> 9;
    const int id   = (row < BQ) ? qids[row * TT + t] : rids[(row - BQ) * TT + t];
    const float4 f = *(const float4*)&emb[(size_t)id * EE + lane * 4];
    *(uint2*)&xseq[(size_t)widx * EE + lane * 4] =
        make_uint2(packh2(f.x, f.y), packh2(f.z, f.w));
}

// ---------------------------------------------------------------------------
// Persistent LSTM: all 160 steps. Grid 256 blocks (1/CU), 4 waves each.
// Block (g=bid&7, bc=bid>>3): rows [g*64,+64), units [bc*16,+16) (=64 cols').
// W panel resident in registers (48 half8/lane). ALL 6 K-chunks staged into
// 6 dedicated LDS buffers at once (latencies overlap); z has its own region.
// 4 barriers/step. Cross-block h via device-coherent sc0|sc1 accesses.
__global__ __launch_bounds__(256, 1) void lstm_persist(
    const unsigned short* __restrict__ Wt,
    const unsigned short* __restrict__ xseq,
    const float* __restrict__ bias,
    const float* __restrict__ wi_, const float* __restrict__ wf_,
    const float* __restrict__ wo_,
    const int* __restrict__ qlen, const int* __restrict__ rlen,
    unsigned short* __restrict__ hbA, unsigned short* __restrict__ hbB,
    unsigned int* __restrict__ bar)
{
    extern __shared__ char smem[];                  // 6*16KB bufs + 16KB zb
    float* zb = (float*)(smem + 98304);             // [64][64] f32, f4-col swz

    const int tid = threadIdx.x;
    const int bid = blockIdx.x;
    const int g   = bid & 7;
    const int bc  = bid >> 3;
    const int rb  = g * 64;
    const int l = tid & 63, w = tid >> 6;
    const int wr = w >> 1, wc = w & 1;

    // ---- resident W fragments: wave covers cols' bc*64 + wc*32 + (l&31)
    half8 wfrag[48];
    {
        const int colp = bc * 64 + wc * 32 + (l & 31);
        const unsigned short* wrow = Wt + (size_t)colp * KK + (l >> 5) * 8;
        #pragma unroll
        for (int f = 0; f < 48; f++) wfrag[f] = *(const half8*)(wrow + 16 * f);
    }

    // ---- epilogue: thread owns 1 row (erow) x 4 contiguous units (eu..eu+3)
    const int erow = tid >> 2;
    const int eu   = (tid & 3) << 2;
    const int Ug0  = bc * 16 + eu;
    const float4 b_i = *(const float4*)&bias[Ug0];
    const float4 b_j = *(const float4*)&bias[HH + Ug0];
    const float4 b_f = *(const float4*)&bias[2 * HH + Ug0];
    const float4 b_o = *(const float4*)&bias[3 * HH + Ug0];
    const float4 wiv = *(const float4*)&wi_[Ug0];
    const float4 wfv = *(const float4*)&wf_[Ug0];
    const float4 wov = *(const float4*)&wo_[Ug0];
    const int len = (rb + erow < BQ) ? qlen[rb + erow] : rlen[rb + erow - BQ];
    float cc[4] = {0.f,0.f,0.f,0.f}, hh[4] = {0.f,0.f,0.f,0.f};

    // stage chunk tk (128 k) of step t into buf tk. Wave w stages rows [w*16,+16).
    // LDS dest linear; XOR-swizzle folded into per-lane SOURCE address (rule #21).
    // h chunks (tk>=2) use device-coherent loads.
    auto stage = [&](int tk, int t, const unsigned short* hsrc) {
        char* base = smem + tk * 16384;
        #pragma unroll
        for (int i2 = 0; i2 < 4; i2++) {
            const int rowbase = w * 16 + i2 * 4;
            const int row = rowbase + (l >> 4);
            const int cch = l & 15;
            const int srcElem = (cch ^ (row & 15)) << 3;
            if (tk < 2) {
                const unsigned short* src =
                    xseq + ((size_t)(t * B2 + rb + row) * EE + tk * 128 + srcElem);
                gload_lds16_c(src, base + rowbase * 256);
            } else {
                const unsigned short* src =
                    hsrc + ((size_t)(rb + row) * HH + (tk - 2) * 128 + srcElem);
                gload_lds16_sc(src, base + rowbase * 256);
            }
        }
    };

    auto compute = [&](int tk, f32x16* a0, f32x16* a1) {
        const char* Ab = smem + tk * 16384;
        const int ra = wr * 32 + (l & 31);
        const int kg = l >> 5;
        #pragma unroll
        for (int f8 = 0; f8 < 8; f8++) {
            const int kc = f8 * 2 + kg;
            half8 av = *(const half8*)(Ab + ra * 256 + (((kc ^ (ra & 15)) << 3) * 2));
            if (f8 & 1) *a1 = __builtin_amdgcn_mfma_f32_32x32x16_f16(av, wfrag[tk * 8 + f8], *a1, 0, 0, 0);
            else        *a0 = __builtin_amdgcn_mfma_f32_32x32x16_f16(av, wfrag[tk * 8 + f8], *a0, 0, 0, 0);
        }
    };

    // prologue: stage step-0 x chunks
    stage(0, 0, hbA);
    stage(1, 0, hbA);
    __syncthreads();

    #pragma unroll 1
    for (int t = 0; t < TT; t++) {
        const unsigned short* hbp = (t & 1) ? hbB : hbA;
        unsigned short* hbq       = (t & 1) ? hbA : hbB;
        f32x16 acc0 = {0,0,0,0,0,0,0,0,0,0,0,0,0,0,0,0};
        f32x16 acc1 = {0,0,0,0,0,0,0,0,0,0,0,0,0,0,0,0};

        // A: x contributions (bufs 0,1 staged last iteration); overlaps spin
        compute(0, &acc0, &acc1);
        compute(1, &acc0, &acc1);
        if (t > 0 && tid == 0) {
            const unsigned int target = 32u * (unsigned)t;
            while (__hip_atomic_load(&bar[g * 16], __ATOMIC_RELAXED,
                                     __HIP_MEMORY_SCOPE_AGENT) < target)
                __builtin_amdgcn_s_sleep(1);
        }
        __syncthreads();                       // h(t) readable; x computes done

        // B: issue ALL stages back-to-back — latencies overlap into ~1 trip
        stage(2, t, hbp);
        stage(3, t, hbp);
        stage(4, t, hbp);
        stage(5, t, hbp);
        if (t < TT - 1) {
            stage(0, t + 1, hbp);              // x of t+1 (cached, no dep)
            stage(1, t + 1, hbp);
        }
        __syncthreads();                       // one vmcnt drain for all

        // C: h-part MFMAs, uninterrupted
        compute(2, &acc0, &acc1);
        compute(3, &acc0, &acc1);
        compute(4, &acc0, &acc1);
        compute(5, &acc0, &acc1);

        // D: z exchange (dedicated region), float4-column XOR swizzle
        {
            const int colb = wc * 32 + (l & 31);
            const int c4i = colb >> 2, cr = colb & 3;
            const f32x16 s = acc0 + acc1;
            #pragma unroll
            for (int r = 0; r < 16; r++) {
                const int row = wr * 32 + 4 * (l >> 5) + (r & 3) + 8 * (r >> 2);
                zb[row * 64 + ((c4i ^ (row & 15)) << 2) + cr] = s[r];
            }
        }
        __syncthreads();

        // E: fused peephole cell (gate order i, j, f, o); 8B coherent h-store
        {
            if (t < len) {
                #pragma unroll
                for (int j = 0; j < 4; j++) {
                    const float4 z4 = *(const float4*)
                        &zb[erow * 64 + (((eu + j) ^ (erow & 15)) << 2)];
                    const float cp = cc[j];
                    const float ig = sigmf(z4.x + (&b_i.x)[j] + (&wiv.x)[j] * cp);
                    const float jg = tanhf(z4.y + (&b_j.x)[j]);
                    const float fg = sigmf(z4.z + (&b_f.x)[j] + 2.0f + (&wfv.x)[j] * cp);
                    const float cn = fg * cp + ig * jg;
                    const float og = sigmf(z4.w + (&b_o.x)[j] + (&wov.x)[j] * cn);
                    cc[j] = cn;
                    hh[j] = og * tanhf(cn);
                }
            }
            union { unsigned short s[4]; unsigned long long v; } pk;
            #pragma unroll
            for (int j = 0; j < 4; j++) pk.s[j] = f2h(hh[j]);
            __hip_atomic_store(
                (unsigned long long*)&hbq[(size_t)(rb + erow) * HH + Ug0], pk.v,
                __ATOMIC_RELAXED, __HIP_MEMORY_SCOPE_AGENT);
        }
        __syncthreads();                       // drains h stores (vmcnt 0)

        // F: post group barrier (release: stores drained at sync above)
        if (t < TT - 1 && tid == 0)
            __hip_atomic_fetch_add(&bar[g * 16], 1u, __ATOMIC_RELAXED,
                                   __HIP_MEMORY_SCOPE_AGENT);
    }
    // 160 steps (even): final h in hbA (q rows 0..255, r rows 256..511)
}

// ---------------------------------------------------------------------------
// q_proj[256,512] = h_q(fp16)[256,512] @ M[512,512]
__global__ __launch_bounds__(512) void proj_kernel(
    const unsigned short* __restrict__ h, const float* __restrict__ M,
    float* __restrict__ qp)
{
    const int i = blockIdx.x;
    const int j = threadIdx.x;
    float s = 0.0f;
    for (int k = 0; k < HH; k++) s += h2f(h[(size_t)i * HH + k]) * M[(size_t)k * HH + j];
    qp[(size_t)i * HH + j] = s;
}

// C[256,256] = A[256,512] @ B(fp16)[256,512]^T
__global__ __launch_bounds__(256) void nt_gemm(
    const float* __restrict__ A,
    const unsigned short* __restrict__ B0, const unsigned short* __restrict__ B1,
    float* __restrict__ C0, float* __restrict__ C1)
{
    const unsigned short* Bm = blockIdx.z ? B1 : B0;
    float* Cm                = blockIdx.z ? C1 : C0;
    __shared__ float sA[16][17];
    __shared__ float sB[16][17];
    const int ti = threadIdx.x >> 4;
    const int tj = threadIdx.x & 15;
    const int ib = blockIdx.y * 16;
    const int jb = blockIdx.x * 16;
    float acc = 0.0f;
    for (int kk = 0; kk < HH; kk += 16) {
        sA[ti][tj] = A[(size_t)(ib + ti) * HH + kk + tj];
        sB[ti][tj] = h2f(Bm[(size_t)(jb + ti) * HH + kk + tj]);
        __syncthreads();
        #pragma unroll
        for (int k = 0; k < 16; k++) acc += sA[ti][k] * sB[tj][k];
        __syncthreads();
    }
    Cm[(size_t)(ib + ti) * 256 + jb + tj] = acc;
}

__global__ void diag_kernel(const float* __restrict__ dist, float* __restrict__ pos) {
    int i = threadIdx.x;
    pos[i] = dist[(size_t)i * 256 + i];
}

// ---------------------------------------------------------------------------
extern "C" void kernel_launch(void* const* d_in, const int* in_sizes, int n_in,
                              void* d_out, int out_size, void* d_ws, size_t ws_size,
                              hipStream_t stream) {
    const int*   qids = (const int*)d_in[0];
    const int*   rids = (const int*)d_in[1];
    const int*   qlen = (const int*)d_in[2];
    const int*   rlen = (const int*)d_in[3];
    const float* emb  = (const float*)d_in[4];
    const float* W    = (const float*)d_in[5];
    const float* bias = (const float*)d_in[6];
    const float* wi   = (const float*)d_in[7];
    const float* wf   = (const float*)d_in[8];
    const float* wo   = (const float*)d_in[9];
    const float* M    = (const float*)d_in[10];

    float* out       = (float*)d_out;
    float* distances = out;
    float* echo      = out + 256 * 256;
    float* pos       = out + 2 * 256 * 256;

    char* ws = (char*)d_ws;
    unsigned short* Wt   = (unsigned short*)(ws);                 // 3,145,728 B
    unsigned short* xseq = (unsigned short*)(ws + 3145728);       // 41,943,040 B
    unsigned short* hbA  = (unsigned short*)(ws + 45088768);      // 524,288 B
    unsigned short* hbB  = (unsigned short*)(ws + 45613056);      // 524,288 B
    float*          qp   = (float*)(ws + 46137344);               // 524,288 B
    unsigned int*   bar  = (unsigned int*)(ws + 46661632);        // 4,096 B

    const int SMEM = 114688;   // 6*16KB chunk bufs + 16KB z
    static int smem_set = 0;
    hipFuncSetAttribute((const void*)lstm_persist,
                        hipFuncAttributeMaxDynamicSharedMemorySize, SMEM);
    (void)smem_set;

    transposeW<<<dim3(64, 24), dim3(256), 0, stream>>>(W, Wt);
    xprep<<<dim3(TT * B2 / 4), dim3(256), 0, stream>>>(emb, qids, rids, xseq);
    hipMemsetAsync(hbA, 0, 524288, stream);
    hipMemsetAsync(bar, 0, 4096, stream);

    lstm_persist<<<dim3(256), dim3(256), SMEM, stream>>>(
        Wt, xseq, bias, wi, wf, wo, qlen, rlen, hbA, hbB, bar);

    proj_kernel<<<dim3(256), dim3(512), 0, stream>>>(hbA, M, qp);
    nt_gemm<<<dim3(16, 16, 2), dim3(256), 0, stream>>>(
        qp, hbA + (size_t)BQ * HH /*r_enc*/, hbA /*q_enc*/, distances, echo);
    diag_kernel<<<dim3(1), dim3(256), 0, stream>>>(distances, pos);
}